// Round 1
// baseline (131.025 us; speedup 1.0000x reference)
//
#include <hip/hip_runtime.h>

// FixedDb4DWT1D: 3-level db4 DWT (depthwise along L, shared filters) +
// bilinear upsample of bands back to L/2, concat on channels.
// x: (32, 16384, 64) f32 -> out: (32, 8192, 256) f32
// out channel blocks: [D1 | up2(D2) | up4(D3) | up4(A3)]

#define NCH 64
#define NB 32
#define L0 16384
#define L1 8192
#define L2 4096
#define L3 2048

// db4 decomposition filters (correlation order, matches lax.conv = no flip)
__device__ constexpr float F_LO[8] = {
    -0.010597401784997278f, 0.032883011666982945f,
    0.030841381835986965f, -0.18703481171888114f,
    -0.02798376941698385f, 0.6308807679295904f,
    0.7148465705525415f,   0.23037781330885523f};
__device__ constexpr float F_HI[8] = {
    -0.23037781330885523f, 0.7148465705525415f,
    -0.6308807679295904f,  -0.02798376941698385f,
    0.18703481171888114f,  0.030841381835986965f,
    0.032883011666982945f, -0.010597401784997278f};

// ---------------- Level 1: x -> D1 (out block 0, identity upsample) + A1 (ws)
__global__ __launch_bounds__(256) void k_level1(const float* __restrict__ x,
                                                float* __restrict__ out,
                                                float* __restrict__ A1) {
  constexpr int TILE = 32;           // level-1 output rows per block
  constexpr int IN = 2 * TILE + 7;   // 71 staged input rows
  __shared__ float s[IN * NCH];
  const int nt = L1 / TILE;          // 256
  const int b = blockIdx.x / nt;
  const int i0 = (blockIdx.x % nt) * TILE;
  const int base_l = 2 * i0 - 3;
  const float* xb = x + (size_t)b * L0 * NCH;

  for (int idx = threadIdx.x; idx < IN * (NCH / 4); idx += 256) {
    const int ll = idx >> 4;         // row (16 float4 per row)
    const int q = idx & 15;
    const int l = base_l + ll;
    float4 v = make_float4(0.f, 0.f, 0.f, 0.f);
    if (l >= 0 && l < L0) v = ((const float4*)(xb + (size_t)l * NCH))[q];
    ((float4*)s)[idx] = v;
  }
  __syncthreads();

  const int c = threadIdx.x & 63;
  const int r0 = threadIdx.x >> 6;
  float* outb = out + (size_t)b * L1 * 256;       // channel block 0
  float* a1b = A1 + (size_t)b * L1 * NCH;
  for (int r = r0; r < TILE; r += 4) {
    float lo = 0.f, hi = 0.f;
#pragma unroll
    for (int t = 0; t < 8; ++t) {
      const float v = s[(2 * r + t) * NCH + c];
      lo = fmaf(v, F_LO[t], lo);
      hi = fmaf(v, F_HI[t], hi);
    }
    const int i = i0 + r;
    outb[(size_t)i * 256 + c] = hi;               // D1 == up(D1)
    a1b[(size_t)i * NCH + c] = lo;                // A1
  }
}

// ---------------- Level 2: A1 -> A2 (ws) + up2(D2) (out block 1)
__global__ __launch_bounds__(256) void k_level2(const float* __restrict__ A1,
                                                float* __restrict__ out,
                                                float* __restrict__ A2) {
  constexpr int TILE = 32;               // level-2 rows per block
  constexpr int DT = TILE + 2;           // 34: rows i0-1 .. i0+TILE (halo 1)
  constexpr int IN = 2 * (DT - 1) + 8;   // 74 staged A1 rows
  __shared__ float sIn[IN * NCH];
  __shared__ float sD[DT * NCH];
  const int nt = L2 / TILE;              // 128
  const int b = blockIdx.x / nt;
  const int i0 = (blockIdx.x % nt) * TILE;
  const int base_l = 2 * i0 - 5;         // = 2*(i0-1) - 3
  const float* inb = A1 + (size_t)b * L1 * NCH;

  for (int idx = threadIdx.x; idx < IN * (NCH / 4); idx += 256) {
    const int ll = idx >> 4;
    const int q = idx & 15;
    const int l = base_l + ll;
    float4 v = make_float4(0.f, 0.f, 0.f, 0.f);
    if (l >= 0 && l < L1) v = ((const float4*)(inb + (size_t)l * NCH))[q];
    ((float4*)sIn)[idx] = v;
  }
  __syncthreads();

  const int c = threadIdx.x & 63;
  const int r0 = threadIdx.x >> 6;
  float* a2b = A2 + (size_t)b * L2 * NCH;
  for (int r = r0; r < DT; r += 4) {     // r=0 <-> level-2 row i0-1
    float lo = 0.f, hi = 0.f;
#pragma unroll
    for (int t = 0; t < 8; ++t) {
      const float v = sIn[(2 * r + t) * NCH + c];
      lo = fmaf(v, F_LO[t], lo);
      hi = fmaf(v, F_HI[t], hi);
    }
    sD[r * NCH + c] = hi;                // D2 (with halo)
    if (r >= 1 && r <= TILE) {
      const int i = i0 - 1 + r;
      a2b[(size_t)i * NCH + c] = lo;     // A2 interior only
    }
  }
  __syncthreads();

  float* outb = out + (size_t)b * L1 * 256 + NCH;  // channel block 1
  for (int r = r0; r < 2 * TILE; r += 4) {
    const int j = 2 * i0 + r;
    const int m = j >> 1;
    int mo = (j & 1) ? m + 1 : m - 1;
    mo = min(max(mo, 0), L2 - 1);
    const float v = 0.75f * sD[(m - (i0 - 1)) * NCH + c] +
                    0.25f * sD[(mo - (i0 - 1)) * NCH + c];
    outb[(size_t)j * 256 + c] = v;
  }
}

// ---------------- Level 3: A2 -> up4(D3) (block 2) + up4(A3) (block 3)
__global__ __launch_bounds__(256) void k_level3(const float* __restrict__ A2,
                                                float* __restrict__ out) {
  constexpr int TILE = 16;               // level-3 rows per block
  constexpr int DT = TILE + 2;           // 18: rows i0-1 .. i0+TILE
  constexpr int IN = 2 * (DT - 1) + 8;   // 42 staged A2 rows
  __shared__ float sIn[IN * NCH];
  __shared__ float sD[DT * NCH];
  __shared__ float sA[DT * NCH];
  const int nt = L3 / TILE;              // 128
  const int b = blockIdx.x / nt;
  const int i0 = (blockIdx.x % nt) * TILE;
  const int base_l = 2 * i0 - 5;
  const float* inb = A2 + (size_t)b * L2 * NCH;

  for (int idx = threadIdx.x; idx < IN * (NCH / 4); idx += 256) {
    const int ll = idx >> 4;
    const int q = idx & 15;
    const int l = base_l + ll;
    float4 v = make_float4(0.f, 0.f, 0.f, 0.f);
    if (l >= 0 && l < L2) v = ((const float4*)(inb + (size_t)l * NCH))[q];
    ((float4*)sIn)[idx] = v;
  }
  __syncthreads();

  const int c = threadIdx.x & 63;
  const int r0 = threadIdx.x >> 6;
  for (int r = r0; r < DT; r += 4) {
    float lo = 0.f, hi = 0.f;
#pragma unroll
    for (int t = 0; t < 8; ++t) {
      const float v = sIn[(2 * r + t) * NCH + c];
      lo = fmaf(v, F_LO[t], lo);
      hi = fmaf(v, F_HI[t], hi);
    }
    sD[r * NCH + c] = hi;
    sA[r * NCH + c] = lo;
  }
  __syncthreads();

  float* outb = out + (size_t)b * L1 * 256;
  for (int r = r0; r < 4 * TILE; r += 4) {
    const int j = 4 * i0 + r;
    const int m = j >> 2;
    const int ph = j & 3;
    const float wo = (ph == 0) ? 0.375f : (ph == 1) ? 0.125f
                   : (ph == 2) ? 0.125f : 0.375f;
    const float wc = 1.0f - wo;
    int mo = (ph < 2) ? m - 1 : m + 1;
    mo = min(max(mo, 0), L3 - 1);
    const int ml = (m - (i0 - 1)) * NCH + c;
    const int mol = (mo - (i0 - 1)) * NCH + c;
    outb[(size_t)j * 256 + 2 * NCH + c] = wc * sD[ml] + wo * sD[mol];  // up4(D3)
    outb[(size_t)j * 256 + 3 * NCH + c] = wc * sA[ml] + wo * sA[mol];  // up4(A3)
  }
}

extern "C" void kernel_launch(void* const* d_in, const int* in_sizes, int n_in,
                              void* d_out, int out_size, void* d_ws, size_t ws_size,
                              hipStream_t stream) {
  const float* x = (const float*)d_in[0];
  float* out = (float*)d_out;
  float* A1 = (float*)d_ws;                         // 32*8192*64 f32 = 64 MiB
  float* A2 = A1 + (size_t)NB * L1 * NCH;           // 32*4096*64 f32 = 32 MiB

  k_level1<<<NB * (L1 / 32), 256, 0, stream>>>(x, out, A1);
  k_level2<<<NB * (L2 / 32), 256, 0, stream>>>(A1, out, A2);
  k_level3<<<NB * (L3 / 16), 256, 0, stream>>>(A2, out);
}